// Round 4
// baseline (139.640 us; speedup 1.0000x reference)
//
#include <hip/hip_runtime.h>

#define NT 256

constexpr int L0 = 8192;
constexpr int N1 = 4099;   // (8192+7)>>1
constexpr int N2 = 2053;   // (4099+7)>>1
constexpr int N3 = 1030;   // (2053+7)>>1
constexpr int N4 = 518;    // (1030+7)>>1
constexpr int ROW_OUT = N4 + N4 + N3 + N2 + N1;  // 8218
constexpr int OFF_A4 = 0;
constexpr int OFF_D4 = 518;
constexpr int OFF_D3 = 1036;
constexpr int OFF_D2 = 2066;
constexpr int OFF_D1 = 4119;

// Per-wave LDS strips (floats): cA1 ext 576 (9/lane), cA2 ext 320 (5/lane),
// cA3 ext 192 (3/lane). Overshoot reads past a strip stay inside the wave's
// 1088-float region (harmless garbage, stores guarded).
constexpr int S1 = 576, S2 = 320, S3 = 192;
constexpr int SW = S1 + S2 + S3;   // 1088 floats = 4352 B per wave

// lo[i] = sum_j GLO[j] * xsym(2i-6+j)   (GLO = pywt db4 rec_lo = dec_lo reversed)
constexpr float GLO[8] = {
    0.23037781330885523f,  0.7148465705525415f,   0.6308807679295904f,
   -0.02798376941698385f, -0.18703481171888114f,  0.030841381835986965f,
    0.032883011666982945f, -0.010597401784997278f };
// hi[i] = sum_j GHI[j] * xsym(2i-6+j)
constexpr float GHI[8] = {
   -0.010597401784997278f, -0.032883011666982945f, 0.030841381835986965f,
    0.18703481171888114f,  -0.02798376941698385f,  -0.6308807679295904f,
    0.7148465705525415f,   -0.23037781330885523f };

// Identical ascending-j fmaf chain as all verified rounds -> bit-exact.
__device__ __forceinline__ void conv1(const float* __restrict__ w,
                                      float& lo, float& hi)
{
    float l = 0.f, h = 0.f;
#pragma unroll
    for (int j = 0; j < 8; ++j) {
        float v = w[j];
        l = fmaf(GLO[j], v, l);
        h = fmaf(GHI[j], v, h);
    }
    lo = l; hi = h;
}

// Barrier-free wave cascade: each wave w of a row independently computes
//   cD1 [512w, ...), cD2 [256w, ...), cD3 [128w, ...), cA4/cD4 [64w, ...)
// with left-halo recompute (cA1 ext from 512w-48, cA2 ext from 256w-18,
// cA3 ext from 128w-6). All level handoffs go through the wave's private LDS
// strips; intra-wave ds_write->ds_read is ordered by the in-order DS pipe,
// so the kernel contains NO __syncthreads at all.
__global__ __launch_bounds__(NT, 8) void wavedec4_db4(const float* __restrict__ x,
                                                      float* __restrict__ out)
{
    __shared__ float lds[4 * SW];   // 17408 B -> 8 blocks/CU = 32 waves/CU
    const int tid = threadIdx.x;
    const int widx = tid >> 6;
    const int l = tid & 63;
    const int gw = blockIdx.x * 4 + widx;   // global wave id
    const int row = gw >> 3;
    const int w = gw & 7;                    // wave's slice of the row

    const float* __restrict__ xr = x + (size_t)row * L0;
    float* __restrict__ outr = out + (size_t)row * ROW_OUT;
    float* __restrict__ s1 = lds + widx * SW;
    float* __restrict__ s2 = s1 + S1;
    float* __restrict__ s3 = s2 + S2;

    const int B1 = 512 * w - 48;             // cA1 ext base
    const int B2 = 256 * w - 18;             // cA2 ext base
    const int B3 = 128 * w - 6;              // cA3 ext base
    const int hi1 = (w == 7) ? N1 : 512 * w + 512;
    const int hi2 = (w == 7) ? N2 : 256 * w + 256;
    const int hi3 = (w == 7) ? N3 : 128 * w + 128;
    const bool interior = (w != 0) && (w != 7);

    // ---- L1: 24 x-floats per lane, 9 cA1/cD1 outputs per lane ----
    float xw[24];
    const int bl = 2 * B1 - 6 + 18 * l;      // x window base (even)
    if (bl >= 0 && bl + 24 <= L0) {
        const float2* p = (const float2*)(xr + bl);
#pragma unroll
        for (int k = 0; k < 12; ++k) { float2 v = p[k]; xw[2 * k] = v.x; xw[2 * k + 1] = v.y; }
    } else {
#pragma unroll
        for (int k = 0; k < 24; ++k) {
            int q = bl + k;
            q = (q < 0) ? (-1 - q) : q;
            q = (q >= L0) ? (2 * L0 - 1 - q) : q;
            xw[k] = xr[q];
        }
    }
#pragma unroll
    for (int m = 0; m < 9; ++m) {
        float lo, hi;
        conv1(xw + 2 * m, lo, hi);
        s1[9 * l + m] = lo;                  // strip pos = c - B1 = 9l+m
        const int c = B1 + 9 * l + m;
        if (c >= 512 * w && c < hi1) outr[OFF_D1 + c] = hi;
    }

    // ---- L2: window = cA1_sym[2c2-6 .. ], c2 = B2 + 5l + m, m<5 ----
    float wb[16];
    if (interior) {
        const float2* p = (const float2*)(s1 + 10 * l + 6);   // pos = 6+10l, even
#pragma unroll
        for (int k = 0; k < 8; ++k) { float2 v = p[k]; wb[2 * k] = v.x; wb[2 * k + 1] = v.y; }
    } else {
        const int g0 = 2 * B2 - 6 + 10 * l;  // level-1 index of window start
#pragma unroll
        for (int k = 0; k < 16; ++k) {
            int g = g0 + k;
            g = (g < 0) ? (-1 - g) : g;
            g = (g >= N1) ? (2 * N1 - 1 - g) : g;
            wb[k] = s1[g - B1];
        }
    }
#pragma unroll
    for (int m = 0; m < 5; ++m) {
        float lo, hi;
        conv1(wb + 2 * m, lo, hi);
        s2[5 * l + m] = lo;                  // strip pos = c - B2 = 5l+m
        const int c = B2 + 5 * l + m;
        if (c >= 256 * w && c < hi2) outr[OFF_D2 + c] = hi;
    }

    // ---- L3: window = cA2_sym[2c3-6 ..], c3 = B3 + 3l + m, m<3 ----
    float wc[12];
    if (interior) {
        const float2* p = (const float2*)(s2 + 6 * l);        // pos = 6l, even
#pragma unroll
        for (int k = 0; k < 6; ++k) { float2 v = p[k]; wc[2 * k] = v.x; wc[2 * k + 1] = v.y; }
    } else {
        const int g0 = 2 * B3 - 6 + 6 * l;
#pragma unroll
        for (int k = 0; k < 12; ++k) {
            int g = g0 + k;
            g = (g < 0) ? (-1 - g) : g;
            g = (g >= N2) ? (2 * N2 - 1 - g) : g;
            wc[k] = s2[g - B2];
        }
    }
#pragma unroll
    for (int m = 0; m < 3; ++m) {
        float lo, hi;
        conv1(wc + 2 * m, lo, hi);
        s3[3 * l + m] = lo;                  // strip pos = c - B3 = 3l+m
        const int c = B3 + 3 * l + m;
        if (c >= 128 * w && c < hi3) outr[OFF_D3 + c] = hi;
    }

    // ---- L4: one output per lane, c4 = 64w + l ----
    float wd[8];
    if (interior) {
        const float2* p = (const float2*)(s3 + 2 * l);        // pos = 2l, even
#pragma unroll
        for (int k = 0; k < 4; ++k) { float2 v = p[k]; wd[2 * k] = v.x; wd[2 * k + 1] = v.y; }
    } else {
        const int g0 = 128 * w - 6 + 2 * l;
#pragma unroll
        for (int k = 0; k < 8; ++k) {
            int g = g0 + k;
            g = (g < 0) ? (-1 - g) : g;
            g = (g >= N3) ? (2 * N3 - 1 - g) : g;
            wd[k] = s3[g - B3];
        }
    }
    {
        float lo, hi;
        conv1(wd, lo, hi);
        const int c = 64 * w + l;
        outr[OFF_A4 + c] = lo;
        outr[OFF_D4 + c] = hi;
    }
    // L4 tail (outputs 512..517), wave 7 lanes 0..5, with right reflection
    if (w == 7 && l < 6) {
        float we[8];
#pragma unroll
        for (int k = 0; k < 8; ++k) {
            int g = 1018 + 2 * l + k;        // 2*(512+l)-6+k
            g = (g >= N3) ? (2 * N3 - 1 - g) : g;
            we[k] = s3[g - B3];
        }
        float lo, hi;
        conv1(we, lo, hi);
        const int c = 512 + l;
        outr[OFF_A4 + c] = lo;
        outr[OFF_D4 + c] = hi;
    }
}

extern "C" void kernel_launch(void* const* d_in, const int* in_sizes, int n_in,
                              void* d_out, int out_size, void* d_ws, size_t ws_size,
                              hipStream_t stream) {
    const float* x = (const float*)d_in[0];
    float* out = (float*)d_out;
    const int rows = in_sizes[0] / L0;   // 64*32 = 2048
    // 8 waves per row, 4 waves per 256-thread block -> 2 blocks per row
    wavedec4_db4<<<dim3(rows * 2), dim3(NT), 0, stream>>>(x, out);
}

// Round 5
// 114.877 us; speedup vs baseline: 1.2156x; 1.2156x over previous
//
#include <hip/hip_runtime.h>

#define NT 512

constexpr int L0 = 8192;
constexpr int N1 = 4099;   // (8192+7)>>1
constexpr int N2 = 2053;   // (4099+7)>>1
constexpr int N3 = 1030;   // (2053+7)>>1
constexpr int N4 = 518;    // (1030+7)>>1
constexpr int ROW_OUT = N4 + N4 + N3 + N2 + N1;  // 8218
constexpr int OFF_A4 = 0;
constexpr int OFF_D4 = 518;
constexpr int OFF_D3 = 1036;
constexpr int OFF_D2 = 2066;
constexpr int OFF_D1 = 4119;

// Halo SoA stride (slots per coefficient lane).
constexpr int HS = 520;

// Union LDS region U (floats), time-shared:
//   L1 phase : T  = U[576*wv .. +576)        per-wave cD1 transpose strips (stride-9 pad)
//   L2+ phase: hB = U[0 .. 2080)             cA2 SoA view [m*HS + t]
//              T2 = U[2080 + 320*wv .. +320) per-wave cD2 transpose strips (stride-5 pad)
// Safe: all T reads complete before barrier 1 (intra-wave DS ordering);
// hB/T2 are only touched after barrier 1.
constexpr int USZ = 4640;

// lo[i] = sum_j GLO[j] * xsym(2i-6+j)   (GLO = pywt db4 rec_lo = dec_lo reversed)
constexpr float GLO[8] = {
    0.23037781330885523f,  0.7148465705525415f,   0.6308807679295904f,
   -0.02798376941698385f, -0.18703481171888114f,  0.030841381835986965f,
    0.032883011666982945f, -0.010597401784997278f };
// hi[i] = sum_j GHI[j] * xsym(2i-6+j)
constexpr float GHI[8] = {
   -0.010597401784997278f, -0.032883011666982945f, 0.030841381835986965f,
    0.18703481171888114f,  -0.02798376941698385f,  -0.6308807679295904f,
    0.7148465705525415f,   -0.23037781330885523f };

// Register-resident cascade (round-3 structure) + wave-local LDS transposes so
// every bulk global store is lane-consecutive (fully coalesced).
__global__ __launch_bounds__(NT, 8) void wavedec4_db4(const float* __restrict__ x,
                                                      float* __restrict__ out)
{
    __shared__ float hA[8 * HS];   // 16640 B : cA1 SoA, later cA3 [g&1][g>>1]
    __shared__ float U[USZ];       // 18560 B : T / hB / T2 (time-shared)
    const int t = threadIdx.x;
    const int wv = t >> 6;         // wave index in block (wave-uniform)
    const int ln = t & 63;         // lane
    const float* __restrict__ xr = x + blockIdx.x * (size_t)L0;
    float* __restrict__ outr = out + blockIdx.x * (size_t)ROW_OUT;

    // ---- load x window [16t-8, 16t+16) into registers, all loads up front ----
    float xw[24];
    if (t > 0) {
        const float4* p = (const float4*)(xr + 16 * t - 8);
        float4 v0 = p[0], v1 = p[1], v2 = p[2], v3 = p[3], v4 = p[4], v5 = p[5];
        xw[0] = v0.x;  xw[1] = v0.y;  xw[2] = v0.z;  xw[3] = v0.w;
        xw[4] = v1.x;  xw[5] = v1.y;  xw[6] = v1.z;  xw[7] = v1.w;
        xw[8] = v2.x;  xw[9] = v2.y;  xw[10] = v2.z; xw[11] = v2.w;
        xw[12] = v3.x; xw[13] = v3.y; xw[14] = v3.z; xw[15] = v3.w;
        xw[16] = v4.x; xw[17] = v4.y; xw[18] = v4.z; xw[19] = v4.w;
        xw[20] = v5.x; xw[21] = v5.y; xw[22] = v5.z; xw[23] = v5.w;
    } else {
        const float4* p = (const float4*)xr;
        float4 v0 = p[0], v1 = p[1], v2 = p[2], v3 = p[3];
        xw[8] = v0.x;  xw[9] = v0.y;  xw[10] = v0.z; xw[11] = v0.w;
        xw[12] = v1.x; xw[13] = v1.y; xw[14] = v1.z; xw[15] = v1.w;
        xw[16] = v2.x; xw[17] = v2.y; xw[18] = v2.z; xw[19] = v2.w;
        xw[20] = v3.x; xw[21] = v3.y; xw[22] = v3.z; xw[23] = v3.w;
#pragma unroll
        for (int k = 0; k < 8; ++k) xw[k] = xw[15 - k];   // xsym(k-8) = x[7-k]
    }

    // ---- L1: outputs i = 8t+m, taps xw[2m+2+j] ----
    float lo1[8];
    float* Tw = U + 576 * wv;
#pragma unroll
    for (int m = 0; m < 8; ++m) {
        float l = 0.f, h = 0.f;
#pragma unroll
        for (int j = 0; j < 8; ++j) {
            float v = xw[2 * m + 2 + j];
            l = fmaf(GLO[j], v, l);
            h = fmaf(GHI[j], v, h);
        }
        lo1[m] = l;
        hA[m * HS + t] = l;
        Tw[9 * ln + m] = h;        // wave-private strip, stride-9 (conflict-free)
    }
    {   // coalesced cD1 stores: chunk k -> c = 512*wv + 64*k + ln (lane-consecutive)
        float* d1 = outr + OFF_D1 + 512 * wv + ln;
        const int rb = 9 * (ln >> 3) + (ln & 7);
#pragma unroll
        for (int k = 0; k < 8; ++k) d1[64 * k] = Tw[72 * k + rb];
    }
    if (t == 8) {   // L1 tail: i = 4096..4098 from x[8186..8191] (+reflection)
        float xt[6];
#pragma unroll
        for (int k = 0; k < 6; ++k) xt[k] = xr[8186 + k];
#pragma unroll
        for (int e = 0; e < 3; ++e) {
            const int i = 4096 + e;
            float l = 0.f, h = 0.f;
#pragma unroll
            for (int j = 0; j < 8; ++j) {
                int q = 2 * i - 6 + j;
                int idx = ((q <= 8191) ? q : (16383 - q)) - 8186;
                float v = xt[idx];
                l = fmaf(GLO[j], v, l);
                h = fmaf(GHI[j], v, h);
            }
            outr[OFF_D1 + i] = h;
            hA[(i & 7) * HS + (i >> 3)] = l;
        }
    }
    __syncthreads();

    // ---- L2: outputs j = 4t+m, taps w2[2m+j'] where w2[k] = cA1[8t-6+k] ----
    float w2[14];
#pragma unroll
    for (int k = 0; k < 6; ++k) {
        int g = 8 * t - 6 + k;
        if (g < 0) g = -1 - g;                 // front reflection (t=0 only)
        w2[k] = hA[(g & 7) * HS + (g >> 3)];
    }
#pragma unroll
    for (int m = 0; m < 8; ++m) w2[6 + m] = lo1[m];
    float lo2[4];
    float* T2w = U + 2080 + 320 * wv;
#pragma unroll
    for (int m = 0; m < 4; ++m) {
        float l = 0.f, h = 0.f;
#pragma unroll
        for (int j = 0; j < 8; ++j) {
            float v = w2[2 * m + j];
            l = fmaf(GLO[j], v, l);
            h = fmaf(GHI[j], v, h);
        }
        lo2[m] = l;
        U[m * HS + t] = l;                     // hB (cA2 SoA)
        T2w[5 * ln + m] = h;                   // wave-private strip, stride-5
    }
    {   // coalesced cD2 stores: chunk k -> c = 256*wv + 64*k + ln
        float* d2 = outr + OFF_D2 + 256 * wv + ln;
        const int rb = 5 * (ln >> 2) + (ln & 3);
#pragma unroll
        for (int k = 0; k < 4; ++k) d2[64 * k] = T2w[80 * k + rb];
    }
    if (t < 5) {    // L2 tail: j = 2048..2052 from published cA1 (+tail reflection)
        const int jj = 2048 + t;
        float l = 0.f, h = 0.f;
#pragma unroll
        for (int j = 0; j < 8; ++j) {
            int g = 2 * jj - 6 + j;
            if (g > 4098) g = 8197 - g;        // reflect at N1
            float v = hA[(g & 7) * HS + (g >> 3)];
            l = fmaf(GLO[j], v, l);
            h = fmaf(GHI[j], v, h);
        }
        outr[OFF_D2 + jj] = h;
        U[(jj & 3) * HS + (jj >> 2)] = l;
    }
    __syncthreads();

    // ---- L3: outputs j = 2t+m, taps w3[2m+j'] where w3[k] = cA2[4t-6+k] ----
    float w3[10];
#pragma unroll
    for (int k = 0; k < 6; ++k) {
        int g = 4 * t - 6 + k;
        if (g < 0) g = -1 - g;
        w3[k] = U[(g & 3) * HS + (g >> 2)];
    }
#pragma unroll
    for (int m = 0; m < 4; ++m) w3[6 + m] = lo2[m];
    float lo3[2];
#pragma unroll
    for (int m = 0; m < 2; ++m) {
        float l = 0.f, h = 0.f;
#pragma unroll
        for (int j = 0; j < 8; ++j) {
            float v = w3[2 * m + j];
            l = fmaf(GLO[j], v, l);
            h = fmaf(GHI[j], v, h);
        }
        lo3[m] = l;
        outr[OFF_D3 + 2 * t + m] = h;
        hA[m * HS + t] = l;                    // cA3 pair view: (2t+m)&1=m, >>1=t
    }
    if (t < 6) {    // L3 tail: j = 1024..1029 from published cA2 (+reflection)
        const int jj = 1024 + t;
        float l = 0.f, h = 0.f;
#pragma unroll
        for (int j = 0; j < 8; ++j) {
            int g = 2 * jj - 6 + j;
            if (g > 2052) g = 4105 - g;        // reflect at N2
            float v = U[(g & 3) * HS + (g >> 2)];
            l = fmaf(GLO[j], v, l);
            h = fmaf(GHI[j], v, h);
        }
        outr[OFF_D3 + jj] = h;
        hA[(jj & 1) * HS + (jj >> 1)] = l;
    }
    __syncthreads();

    // ---- L4: output j = t, taps w4[j'] where w4[k] = cA3[2t-6+k] ----
    float w4[8];
#pragma unroll
    for (int k = 0; k < 6; ++k) {
        int g = 2 * t - 6 + k;
        if (g < 0) g = -1 - g;
        w4[k] = hA[(g & 1) * HS + (g >> 1)];
    }
    w4[6] = lo3[0];
    w4[7] = lo3[1];
    {
        float l = 0.f, h = 0.f;
#pragma unroll
        for (int j = 0; j < 8; ++j) {
            float v = w4[j];
            l = fmaf(GLO[j], v, l);
            h = fmaf(GHI[j], v, h);
        }
        outr[OFF_A4 + t] = l;      // lane-consecutive (coalesced)
        outr[OFF_D4 + t] = h;
    }
    if (t < 6) {    // L4 tail: j = 512..517 from published cA3 (+reflection)
        const int jj = 512 + t;
        float l = 0.f, h = 0.f;
#pragma unroll
        for (int j = 0; j < 8; ++j) {
            int g = 2 * jj - 6 + j;
            if (g > 1029) g = 2059 - g;        // reflect at N3
            float v = hA[(g & 1) * HS + (g >> 1)];
            l = fmaf(GLO[j], v, l);
            h = fmaf(GHI[j], v, h);
        }
        outr[OFF_A4 + jj] = l;
        outr[OFF_D4 + jj] = h;
    }
}

extern "C" void kernel_launch(void* const* d_in, const int* in_sizes, int n_in,
                              void* d_out, int out_size, void* d_ws, size_t ws_size,
                              hipStream_t stream) {
    const float* x = (const float*)d_in[0];
    float* out = (float*)d_out;
    const int rows = in_sizes[0] / L0;  // 64*32 = 2048
    wavedec4_db4<<<dim3(rows), dim3(NT), 0, stream>>>(x, out);
}